// Round 1
// baseline (68.330 us; speedup 1.0000x reference)
//
#include <hip/hip_runtime.h>
#include <math.h>

// 4-qubit quanvolution: one thread per 2x2 patch.
// amp index: i = b0*8 + b1*4 + b2*2 + b3  (bit of qubit q is bit (3-q) of i)

__global__ __launch_bounds__(256) void quanv_kernel(
    const float* __restrict__ x, const float* __restrict__ w,
    float* __restrict__ out, int total)
{
    int tid = blockIdx.x * blockDim.x + threadIdx.x;
    if (tid >= total) return;

    int b  = tid >> 10;       // batch (1024 patches per image)
    int pl = tid & 1023;
    int r  = pl >> 5;         // patch row 0..31
    int c  = pl & 31;         // patch col 0..31

    // x is (512,1,64,64): element [b,0,row,col] at b*4096 + row*64 + col
    const float* p0 = x + ((size_t)b << 12) + (r << 7) + (c << 1);
    float2 t0 = *reinterpret_cast<const float2*>(p0);        // row 2r:  a0, a1
    float2 t1 = *reinterpret_cast<const float2*>(p0 + 64);   // row 2r+1: a2, a3

    // encoding sincos
    float c0, s0, c1, s1, c2, s2, c3, s3;
    __sincosf(0.5f * t0.x, &s0, &c0);
    __sincosf(0.5f * t0.y, &s1, &c1);
    __sincosf(0.5f * t1.x, &s2, &c2);
    __sincosf(0.5f * t1.y, &s3, &c3);

    // v0 = RY(a1) RZ(a0) [1,1]^T ;  v1 = RY(a3) RZ(a2) [1,1]^T
    float v00r = (c1 - s1) * c0, v00i = -(c1 + s1) * s0;
    float v01r = (c1 + s1) * c0, v01i =  (c1 - s1) * s0;
    float v10r = (c3 - s3) * c2, v10i = -(c3 + s3) * s2;
    float v11r = (c3 + s3) * c2, v11i =  (c3 - s3) * s2;

    // weight sincos (wave-uniform values, cheap)
    float wc[8], ws[8];
    #pragma unroll
    for (int k = 0; k < 8; ++k) {
        __sincosf(0.5f * w[k], &ws[k], &wc[k]);
    }

    // build 16 amplitudes: amp(i) = 0.25 * v0[b0] * v1[b1]
    float ar[16], ai[16];
    #pragma unroll
    for (int i = 0; i < 16; ++i) {
        float pr = ((i >> 3) & 1) ? v01r : v00r;
        float pi_ = ((i >> 3) & 1) ? v01i : v00i;
        float qr = ((i >> 2) & 1) ? v11r : v10r;
        float qi = ((i >> 2) & 1) ? v11i : v10i;
        ar[i] = 0.25f * (pr * qr - pi_ * qi);
        ai[i] = 0.25f * (pr * qi + pi_ * qr);
    }

    // CRZ ring: control g, target (g+1)%4, angle w[g]
    #pragma unroll
    for (int g = 0; g < 4; ++g) {
        const int cq = g, tq = (g + 1) & 3;
        const int mc = 1 << (3 - cq);
        const int mt = 1 << (3 - tq);
        #pragma unroll
        for (int i = 0; i < 16; ++i) {
            if (i & mc) {
                float pr = wc[g];
                float pim = (i & mt) ? ws[g] : -ws[g];
                float nr = ar[i] * pr - ai[i] * pim;
                float ni = ar[i] * pim + ai[i] * pr;
                ar[i] = nr; ai[i] = ni;
            }
        }
    }

    // RY layer: RY(w[4+q]) on qubit q
    #pragma unroll
    for (int q = 0; q < 4; ++q) {
        const float cc = wc[4 + q], ss = ws[4 + q];
        const int m = 1 << (3 - q);
        #pragma unroll
        for (int i = 0; i < 16; ++i) {
            if (!(i & m)) {
                const int j = i | m;
                float x0r = ar[i], x0i = ai[i];
                float x1r = ar[j], x1i = ai[j];
                ar[i] = cc * x0r - ss * x1r;
                ai[i] = cc * x0i - ss * x1i;
                ar[j] = ss * x0r + cc * x1r;
                ai[j] = ss * x0i + cc * x1i;
            }
        }
    }

    // <Z_q> = sum_i |amp_i|^2 * (+1 if bit_q(i)==0 else -1)
    float ev0 = 0.f, ev1 = 0.f, ev2 = 0.f, ev3 = 0.f;
    #pragma unroll
    for (int i = 0; i < 16; ++i) {
        float p = ar[i] * ar[i] + ai[i] * ai[i];
        ev0 += (i & 8) ? -p : p;
        ev1 += (i & 4) ? -p : p;
        ev2 += (i & 2) ? -p : p;
        ev3 += (i & 1) ? -p : p;
    }

    float4 o = make_float4(ev0, ev1, ev2, ev3);
    *reinterpret_cast<float4*>(out + ((size_t)tid << 2)) = o;
}

extern "C" void kernel_launch(void* const* d_in, const int* in_sizes, int n_in,
                              void* d_out, int out_size, void* d_ws, size_t ws_size,
                              hipStream_t stream) {
    const float* x = (const float*)d_in[0];   // (512,1,64,64) fp32
    const float* w = (const float*)d_in[1];   // (1,8) fp32
    float* out = (float*)d_out;               // (512,4096) fp32

    int total = in_sizes[0] >> 2;             // one thread per 2x2 patch
    int block = 256;
    int grid = (total + block - 1) / block;
    quanv_kernel<<<grid, block, 0, stream>>>(x, w, out, total);
}

// Round 4
// 60.285 us; speedup vs baseline: 1.1335x; 1.1335x over previous
//
#include <hip/hip_runtime.h>
#include <math.h>

// Quanvolution, closed form (symbolically verified round 2).
//
// Per patch (angles a0..a3), with weights th0..th3 (CRZ) and t0..t3 (RY):
//   encoded per-qubit vectors give:
//     Z0 = sin(a1)cos(a0),  X0r = cos(a1)cos(a0),  X0i = sin(a0)
//     Z1 = sin(a3)cos(a2),  X1r = cos(a3)cos(a2),  X1i = sin(a2)
//   (qubits 2,3 remain |+>; CRZ is diagonal & unit-modulus; final RY layer
//    commuted into the observable: O_q = cos(t_q) Z - sin(t_q) X)
//   ev0 = -cos(t0)*Z0 + k1*X0r + k2*X0i + Z1*(k3*X0r + k4*X0i)
//   ev1 = -cos(t1)*Z1 + m1*X1r + m3*X1i + Z0*(m2*X1r + m3*X1i)
//   ev2 = n0 + n1*Z1
//   ev3 = p0 + p1*Z0
// with weight-only coefficients k/m/n/p.

__global__ __launch_bounds__(256) void quanv_kernel(
    const float* __restrict__ x, const float* __restrict__ w,
    float* __restrict__ out, int total)
{
    int tid = blockIdx.x * blockDim.x + threadIdx.x;
    if (tid >= total) return;

    // ---- uniform (weight-only) coefficients
    const float th0 = w[0], th1 = w[1], th2 = w[2], th3 = w[3];
    const float t0 = w[4], t1 = w[5], t2 = w[6], t3 = w[7];

    const float c0h = __cosf(0.5f * th0), s0h = __sinf(0.5f * th0);
    const float c0f = __cosf(th0),        s0f = __sinf(th0);
    const float c1f = __cosf(th1),        c1h = __cosf(0.5f * th1);
    const float c2f = __cosf(th2),        s2f = __sinf(th2);
    const float c2h = __cosf(0.5f * th2);
    const float c3f = __cosf(th3),        s3f = __sinf(th3);
    const float c3h = __cosf(0.5f * th3), s3h = __sinf(0.5f * th3);

    const float ct0 = __cosf(t0), st0 = __sinf(t0);
    const float ct1 = __cosf(t1), st1 = __sinf(t1);
    const float st2 = __sinf(t2);
    const float st3 = __sinf(t3);

    const float k1 = -0.5f * st0 * (1.f + c3f) * c0h;
    const float k2 =  0.5f * st0 * s3f * c0h;
    const float k3 =  0.5f * st0 * s3f * s0h;
    const float k4 =  0.5f * st0 * (1.f + c3f) * s0h;

    const float mb = 0.5f * st1 * c1h;
    const float m1 = -mb * (1.f + c0f);
    const float m2 = -mb * (c0f - 1.f);
    const float m3 =  mb * s0f;
    const float nb = 0.5f * st2 * c2h;
    const float n0 = -nb * (1.f + c1f);
    const float n1 = -nb * (c1f - 1.f);
    const float p0 = -0.5f * st3 * (1.f + c2f) * c3h;
    const float p1 =  0.5f * st3 * s2f * s3h;

    // ---- 2 patches per thread: 16 B/lane loads, 32 B/lane stores
    int b  = tid >> 9;
    int rm = tid & 511;
    int r  = rm >> 4;
    int cp = rm & 15;

    const float* src = x + ((size_t)b << 12) + (r << 7) + (cp << 2);
    float4 row0 = *reinterpret_cast<const float4*>(src);        // image row 2r
    float4 row1 = *reinterpret_cast<const float4*>(src + 64);   // image row 2r+1

    float4 o[2];
    #pragma unroll
    for (int p = 0; p < 2; ++p) {
        float a0 = p ? row0.z : row0.x;
        float a1 = p ? row0.w : row0.y;
        float a2 = p ? row1.z : row1.x;
        float a3 = p ? row1.w : row1.y;

        float sa0 = __sinf(a0), ca0 = __cosf(a0);
        float sa1 = __sinf(a1), ca1 = __cosf(a1);
        float sa2 = __sinf(a2), ca2 = __cosf(a2);
        float sa3 = __sinf(a3), ca3 = __cosf(a3);

        float Z0  = sa1 * ca0;
        float X0r = ca1 * ca0;
        float X0i = sa0;
        float Z1  = sa3 * ca2;
        float X1r = ca3 * ca2;
        float X1i = sa2;

        float ev0 = -ct0 * Z0 + k1 * X0r + k2 * X0i + Z1 * (k3 * X0r + k4 * X0i);
        float ev1 = -ct1 * Z1 + m1 * X1r + m3 * X1i + Z0 * (m2 * X1r + m3 * X1i);
        float ev2 = n0 + n1 * Z1;
        float ev3 = p0 + p1 * Z0;
        o[p] = make_float4(ev0, ev1, ev2, ev3);
    }

    float* dst = out + ((size_t)tid << 3);
    *reinterpret_cast<float4*>(dst)     = o[0];
    *reinterpret_cast<float4*>(dst + 4) = o[1];
}

extern "C" void kernel_launch(void* const* d_in, const int* in_sizes, int n_in,
                              void* d_out, int out_size, void* d_ws, size_t ws_size,
                              hipStream_t stream) {
    const float* x = (const float*)d_in[0];   // (512,1,64,64) fp32
    const float* w = (const float*)d_in[1];   // (1,8) fp32
    float* out = (float*)d_out;               // (512,4096) fp32

    int total = in_sizes[0] >> 3;             // one thread per 2 patches
    int block = 256;
    int grid = (total + block - 1) / block;
    quanv_kernel<<<grid, block, 0, stream>>>(x, w, out, total);
}